// Round 9
// baseline (377.184 us; speedup 1.0000x reference)
//
#include <hip/hip_runtime.h>
#include <hip/hip_bf16.h>
#include <stdint.h>

#define DIM 128
#define NH 8
#define CH 4096          // edges per bucketing block
#define BK 128           // nodes per bucket (K = ceil(N/128) <= 1024 for N <= 131072)
#define LS 136           // LDS row stride in shorts: 272B rows -> 16B-aligned b128; reads 2-way (free)

using bf16 = __hip_bfloat16;
typedef __attribute__((ext_vector_type(8))) short short8;
typedef __attribute__((ext_vector_type(4))) float floatx4;

// head-major permutation: orig dim d -> pos(d) = (d&7)*16 + (d>>3)
// inverse: position kt -> orig(kt) = (kt&15)*8 + (kt>>4)

__device__ inline float bf2f(unsigned short b) {
    return __uint_as_float(((unsigned)b) << 16);
}
__device__ inline unsigned short f2bf(float f) {
    unsigned u = __float_as_uint(f);
    u += 0x7FFFu + ((u >> 16) & 1u);   // RNE
    return (unsigned short)(u >> 16);
}

__device__ inline float gelu_tanh(float x) {
    float x3 = x * x * x;
    float u = 0.7978845608028654f * (x + 0.044715f * x3);
    float e = __expf(2.f * u);
    float t = 1.f - 2.f / (e + 1.f);   // tanh(u), safe at +/-inf
    return 0.5f * x * (1.f + t);
}

// ============ one-off weight pre-conversion to bf16, transposed wt[n][k] layout ============
__launch_bounds__(256)
__global__ void preconv_kernel(const float* __restrict__ w_in, const float* __restrict__ w1,
                               const float* __restrict__ w2, const float* __restrict__ w_au,
                               const float* __restrict__ w_av,
                               unsigned short* __restrict__ w_in_b, unsigned short* __restrict__ w1_b,
                               unsigned short* __restrict__ w2_b, unsigned short* __restrict__ wc_b) {
    const int b = blockIdx.x, tid = threadIdx.x;
    if (b < 12) {
        const int m = b >> 2, qtr = b & 3;
        const float* W = m == 0 ? w_in : (m == 1 ? w1 : w2);
        unsigned short* O = m == 0 ? w_in_b : (m == 1 ? w1_b : w2_b);
        const bool perm = (m == 1);
        #pragma unroll
        for (int i = 0; i < 16; ++i) {
            int o = qtr * 4096 + tid + i * 256;   // o = n*128 + k
            int k = o & 127, n = o >> 7;
            int krow = perm ? ((k & 15) * 8 + (k >> 4)) : k;
            O[o] = f2bf(W[krow * 128 + n]);
        }
    } else {
        #pragma unroll
        for (int i = 0; i < 8; ++i) {
            int o = tid + i * 256;                // o = j*128 + kt
            int j = o >> 7, kt = o & 127;
            int ko = (kt & 15) * 8 + (kt >> 4);
            float v = (j < 8) ? w_au[ko * 8 + j] : w_av[ko * 8 + (j - 8)];
            wc_b[o] = f2bf(v);
        }
    }
}

// ============ fused: h = x@w_in + b_in (head-major bf16) ; au/av via MFMA ============
// Weights read DIRECTLY from global bf16 (32 KB, L1/L2-resident: every wave reads the
// same fragment lines). LDS holds only the 128-row h tile. One barrier.
__launch_bounds__(512)
__global__ void gemm_in_attn_kernel(const float* __restrict__ x, const unsigned short* __restrict__ w_in_b,
                                    const float* __restrict__ b_in,
                                    const unsigned short* __restrict__ wc_b, const float* __restrict__ b_au,
                                    bf16* __restrict__ h, float* __restrict__ au,
                                    float* __restrict__ av, int M) {
    __shared__ __align__(16) unsigned short ht[128 * LS];   // head-major h tile
    const int tid = threadIdx.x;
    const int wave = tid >> 6;
    const int lane = tid & 63;
    const int l15 = lane & 15;
    const int q = lane >> 4;
    const int rowbase = blockIdx.x * 128 + wave * 16;
    const int rowA = min(rowbase + l15, M - 1);

    floatx4 acc[8];
    #pragma unroll
    for (int c = 0; c < 8; ++c) acc[c] = (floatx4){0.f, 0.f, 0.f, 0.f};

    #pragma unroll
    for (int kk = 0; kk < 4; ++kk) {
        const float* ap = x + (size_t)rowA * 128 + kk * 32 + q * 8;
        floatx4 a0 = *(const floatx4*)ap;
        floatx4 a1 = *(const floatx4*)(ap + 4);
        union { short8 s; unsigned short u[8]; } cv;
        #pragma unroll
        for (int j = 0; j < 4; ++j) { cv.u[j] = f2bf(a0[j]); cv.u[4 + j] = f2bf(a1[j]); }
        short8 afrag = cv.s;
        #pragma unroll
        for (int c = 0; c < 8; ++c) {
            short8 bfrag = *(const short8*)(w_in_b + (c * 16 + l15) * 128 + kk * 32 + q * 8);
            acc[c] = __builtin_amdgcn_mfma_f32_16x16x32_bf16(afrag, bfrag, acc[c], 0, 0, 0);
        }
    }

    // write h tile (head-major) to LDS
    const int rl0 = wave * 16 + q * 4;
    #pragma unroll
    for (int c = 0; c < 8; ++c) {
        int col = c * 16 + l15;
        int colw = (col & 7) * 16 + (col >> 3);   // head-major position
        float b = b_in[col];
        #pragma unroll
        for (int r = 0; r < 4; ++r)
            ht[(rl0 + r) * LS + colw] = f2bf(acc[c][r] + b);
    }
    __syncthreads();

    // coalesced h write from LDS tile (b128)
    const int blk0 = blockIdx.x * 128;
    #pragma unroll
    for (int i = 0; i < 4; ++i) {
        int g = tid + i * 512;                 // row = g>>4, blk = g&15
        int row = g >> 4;
        if (blk0 + row < M) {
            short8 v = *(const short8*)(ht + row * LS + (g & 15) * 8);
            *(short8*)((unsigned short*)h + (size_t)(blk0 + row) * 128 + (g & 15) * 8) = v;
        }
    }

    // au/av: one MFMA chain; A = own wave's ht rows (same-wave LDS RAW is in-order),
    // B = wc_b direct from global (4 KB)
    floatx4 acc2 = (floatx4){0.f, 0.f, 0.f, 0.f};
    #pragma unroll
    for (int kk = 0; kk < 4; ++kk) {
        short8 af = *(const short8*)(ht + (wave * 16 + l15) * LS + kk * 32 + q * 8);
        short8 bf = *(const short8*)(wc_b + l15 * 128 + kk * 32 + q * 8);
        acc2 = __builtin_amdgcn_mfma_f32_16x16x32_bf16(af, bf, acc2, 0, 0, 0);
    }
    {
        const int row0 = rowbase + q * 4;
        int col = l15;
        #pragma unroll
        for (int r = 0; r < 4; ++r) {
            int rr = row0 + r;
            if (rr < M) {
                if (col < 8) au[(size_t)rr * 8 + col] = acc2[r] + b_au[col];
                else         av[(size_t)rr * 8 + (col - 8)] = acc2[r];
            }
        }
    }
}

// ============ fused FF: out = gelu(A@w1 + b1) @ w2 + b2 (A head-major bf16) ============
// Weights direct from global bf16 (w1_b PERM pre-applied). LDS = hidden tile only
// (34.8 KB -> 4 blocks/CU, thread-cap). One barrier.
__launch_bounds__(512)
__global__ void ff_kernel(const bf16* __restrict__ A, const unsigned short* __restrict__ w1_b,
                          const float* __restrict__ b1, const unsigned short* __restrict__ w2_b,
                          const float* __restrict__ b2, float* __restrict__ out, int M) {
    __shared__ __align__(16) unsigned short ht[128 * LS];
    const int tid = threadIdx.x;
    const int wave = tid >> 6;
    const int lane = tid & 63;
    const int l15 = lane & 15;
    const int q = lane >> 4;
    const int rowbase = blockIdx.x * 128 + wave * 16;
    const int rowA = min(rowbase + l15, M - 1);

    floatx4 acc[8];
    #pragma unroll
    for (int c = 0; c < 8; ++c) acc[c] = (floatx4){0.f, 0.f, 0.f, 0.f};

    #pragma unroll
    for (int kk = 0; kk < 4; ++kk) {
        short8 afrag = *(const short8*)((const unsigned short*)A + (size_t)rowA * 128 + kk * 32 + q * 8);
        #pragma unroll
        for (int c = 0; c < 8; ++c) {
            short8 bfrag = *(const short8*)(w1_b + (c * 16 + l15) * 128 + kk * 32 + q * 8);
            acc[c] = __builtin_amdgcn_mfma_f32_16x16x32_bf16(afrag, bfrag, acc[c], 0, 0, 0);
        }
    }

    // gelu(hidden) -> LDS tile
    const int rl0 = wave * 16 + q * 4;
    #pragma unroll
    for (int c = 0; c < 8; ++c) {
        int col = c * 16 + l15;
        float b = b1[col];
        #pragma unroll
        for (int r = 0; r < 4; ++r)
            ht[(rl0 + r) * LS + col] = f2bf(gelu_tanh(acc[c][r] + b));
    }
    __syncthreads();   // (own-wave rows would suffice; barrier kept for safety)

    floatx4 acc2[8];
    #pragma unroll
    for (int c = 0; c < 8; ++c) acc2[c] = (floatx4){0.f, 0.f, 0.f, 0.f};
    #pragma unroll
    for (int kk = 0; kk < 4; ++kk) {
        short8 af = *(const short8*)(ht + (wave * 16 + l15) * LS + kk * 32 + q * 8);
        #pragma unroll
        for (int c = 0; c < 8; ++c) {
            short8 bfrag = *(const short8*)(w2_b + (c * 16 + l15) * 128 + kk * 32 + q * 8);
            acc2[c] = __builtin_amdgcn_mfma_f32_16x16x32_bf16(af, bfrag, acc2[c], 0, 0, 0);
        }
    }

    const int row0 = rowbase + q * 4;
    #pragma unroll
    for (int c = 0; c < 8; ++c) {
        int col = c * 16 + l15;
        float b = b2[col];
        #pragma unroll
        for (int r = 0; r < 4; ++r) {
            int rr = row0 + r;
            if (rr < M) out[(size_t)rr * 128 + col] = acc2[c][r] + b;
        }
    }
}

// ======================= atomic-free CSR build (LDS multisplit) =======================

__launch_bounds__(256)
__global__ void bucket_count_kernel(const int* __restrict__ dst, int* __restrict__ mat,
                                    int E, int K, int B) {
    __shared__ int cnt[1024];
    const int b = blockIdx.x;
    for (int k = threadIdx.x; k < K; k += 256) cnt[k] = 0;
    __syncthreads();
    const int base = b * CH, end = min(base + CH, E);
    for (int i = base + threadIdx.x; i < end; i += 256)
        atomicAdd(&cnt[dst[i] >> 7], 1);
    __syncthreads();
    for (int k = threadIdx.x; k < K; k += 256) mat[(size_t)k * B + b] = cnt[k];
}

__launch_bounds__(64)
__global__ void scan_bucket_kernel(int* __restrict__ mat, int* __restrict__ btot, int B) {
    const int k = blockIdx.x;
    const int lane = threadIdx.x;
    const size_t base = (size_t)k * B;
    int carry = 0;
    for (int i0 = 0; i0 < B; i0 += 64) {
        int idx = i0 + lane;
        int v = (idx < B) ? mat[base + idx] : 0;
        int incl = v;
        #pragma unroll
        for (int off = 1; off < 64; off <<= 1) {
            int y = __shfl_up(incl, off);
            if (lane >= off) incl += y;
        }
        int tot = __shfl(incl, 63);
        if (idx < B) mat[base + idx] = carry + incl - v;
        carry += tot;
    }
    if (lane == 0) btot[k] = carry;
}

__launch_bounds__(64)
__global__ void scan_total_kernel(const int* __restrict__ btot, int* __restrict__ bbase, int K) {
    const int lane = threadIdx.x;
    int carry = 0;
    for (int i0 = 0; i0 < K; i0 += 64) {
        int idx = i0 + lane;
        int v = (idx < K) ? btot[idx] : 0;
        int incl = v;
        #pragma unroll
        for (int off = 1; off < 64; off <<= 1) {
            int y = __shfl_up(incl, off);
            if (lane >= off) incl += y;
        }
        int tot = __shfl(incl, 63);
        if (idx < K) bbase[idx] = carry + incl - v;
        carry += tot;
    }
}

__launch_bounds__(256)
__global__ void bucket_scatter_kernel(const int* __restrict__ src, const int* __restrict__ dst,
                                      const int* __restrict__ mat, const int* __restrict__ bbase,
                                      unsigned* __restrict__ packed, int E, int K, int B) {
    __shared__ int cur[1024];
    const int b = blockIdx.x;
    for (int k = threadIdx.x; k < K; k += 256)
        cur[k] = bbase[k] + mat[(size_t)k * B + b];
    __syncthreads();
    const int base = b * CH, end = min(base + CH, E);
    for (int i = base + threadIdx.x; i < end; i += 256) {
        int d = dst[i], s = src[i];
        int pos = atomicAdd(&cur[d >> 7], 1);
        packed[pos] = (unsigned)s | ((unsigned)(d & 127) << 20);
    }
}

__launch_bounds__(256)
__global__ void bucket_csr_kernel(const unsigned* __restrict__ packed,
                                  const int* __restrict__ bbase, const int* __restrict__ btot,
                                  int* __restrict__ rowptr, int* __restrict__ deg,
                                  int* __restrict__ esrc, int N) {
    __shared__ int hist[128], cur[128];
    __shared__ int wtot;
    const int k = blockIdx.x;
    const int tid = threadIdx.x;
    const int lane = tid & 63;
    const int start = bbase[k];
    const int cnt = btot[k];

    if (tid < 128) hist[tid] = 0;
    __syncthreads();
    for (int i = tid; i < cnt; i += 256)
        atomicAdd(&hist[packed[start + i] >> 20], 1);
    __syncthreads();

    int v = (tid < 128) ? hist[tid] : 0;
    int incl = v;
    #pragma unroll
    for (int off = 1; off < 64; off <<= 1) {
        int y = __shfl_up(incl, off);
        if (lane >= off) incl += y;
    }
    if (tid == 63) wtot = incl;       // total of nodes 0..63
    __syncthreads();
    int excl = incl - v + ((tid >= 64 && tid < 128) ? wtot : 0);
    if (tid < 128) {
        int n = k * BK + tid;
        if (n < N) { rowptr[n] = start + excl; deg[n] = v; }
        cur[tid] = excl;
    }
    __syncthreads();

    for (int i = tid; i < cnt; i += 256) {
        unsigned p = packed[start + i];
        int pos = atomicAdd(&cur[p >> 20], 1);
        esrc[start + pos] = (int)(p & 0xFFFFFu);
    }
}

// ======================= fused softmax aggregation (CSR, head-major) =======================
// One wave per node, 8 edges in flight: 8 lanes per edge, lane owns ONE full head
// (16 contiguous head-major dims, 2 x b128 loads). 8 exps per edge.
// No max-subtraction: scores = leaky(au+av) bounded ~|8| -> exp <= ~3e3, safe.

__device__ __forceinline__ void unpack8fma(uint4 w, float p, float* o) {
    o[0] = fmaf(p, __uint_as_float(w.x << 16), o[0]);
    o[1] = fmaf(p, __uint_as_float(w.x & 0xFFFF0000u), o[1]);
    o[2] = fmaf(p, __uint_as_float(w.y << 16), o[2]);
    o[3] = fmaf(p, __uint_as_float(w.y & 0xFFFF0000u), o[3]);
    o[4] = fmaf(p, __uint_as_float(w.z << 16), o[4]);
    o[5] = fmaf(p, __uint_as_float(w.z & 0xFFFF0000u), o[5]);
    o[6] = fmaf(p, __uint_as_float(w.w << 16), o[6]);
    o[7] = fmaf(p, __uint_as_float(w.w & 0xFFFF0000u), o[7]);
}

template <bool MASKED>
__device__ __forceinline__ void do8e(const int* __restrict__ ep, int i, int nd,
                                     int e, int head, int d0b,
                                     const float* __restrict__ au,
                                     const char* __restrict__ hpb,
                                     float avh, float& l, float* o) {
    int idx = i + e;
    int s;
    float m = 1.f;
    if constexpr (MASKED) {
        s = ep[min(idx, nd - 1)];
        m = idx < nd ? 1.f : 0.f;
    } else {
        s = ep[idx];
    }
    float a = au[(s << 3) + head];
    size_t off = ((size_t)(unsigned)s) << 8;        // 256 B per node row
    uint4 w0 = *(const uint4*)(hpb + off + d0b);
    uint4 w1 = *(const uint4*)(hpb + off + d0b + 16);
    float x = a + avh;
    x = fmaxf(x, 0.2f * x);          // LeakyReLU(0.2)
    float p = __expf(x);
    if constexpr (MASKED) p *= m;
    l += p;
    unpack8fma(w0, p, o);
    unpack8fma(w1, p, o + 8);
}

__launch_bounds__(256)
__global__ void agg_csr_kernel(const int* __restrict__ rowptr, const int* __restrict__ deg,
                               const int* __restrict__ esrc,
                               const float* __restrict__ au, const float* __restrict__ av,
                               const bf16* __restrict__ h, bf16* __restrict__ agg, int N) {
    const int node = (blockIdx.x * 256 + threadIdx.x) >> 6;
    if (node >= N) return;
    const int lane = threadIdx.x & 63;
    const int e = lane >> 3;          // which edge of the 8-batch
    const int head = lane & 7;        // lane's single head
    const int d0b = head * 32;        // byte offset of its 16 head-major dims
    const char* hpb = (const char*)h;
    const int nd = deg[node];
    const int start = rowptr[node];
    const float avh = av[((size_t)node << 3) + head];
    const int* ep = esrc + start;

    float l0 = 0.f;
    float o[16];
    #pragma unroll
    for (int j = 0; j < 16; ++j) o[j] = 0.f;

    int i = 0;
    for (; i + 16 <= nd; i += 16) {
        do8e<false>(ep, i, nd, e, head, d0b, au, hpb, avh, l0, o);
        do8e<false>(ep, i + 8, nd, e, head, d0b, au, hpb, avh, l0, o);
    }
    if (i + 8 <= nd) { do8e<false>(ep, i, nd, e, head, d0b, au, hpb, avh, l0, o); i += 8; }
    if (i < nd) do8e<true>(ep, i, nd, e, head, d0b, au, hpb, avh, l0, o);

    // sum the 8 edge-groups (lanes l, l^8, l^16, ..., l^56 own the same dims)
    #pragma unroll
    for (int j = 0; j < 16; ++j) {
        o[j] += __shfl_xor(o[j], 8);
        o[j] += __shfl_xor(o[j], 16);
        o[j] += __shfl_xor(o[j], 32);
    }
    l0 += __shfl_xor(l0, 8);
    l0 += __shfl_xor(l0, 16);
    l0 += __shfl_xor(l0, 32);

    if (lane < 8) {
        float inv = l0 > 0.f ? 1.f / l0 : 0.f;   // deg-0 -> 0 (matches segment_sum)
        unsigned r[8];
        #pragma unroll
        for (int j = 0; j < 8; ++j)
            r[j] = ((unsigned)f2bf(o[2 * j + 1] * inv) << 16) | (unsigned)f2bf(o[2 * j] * inv);
        char* outp = (char*)agg + ((size_t)node << 8) + lane * 32;
        *(uint4*)outp = (uint4){r[0], r[1], r[2], r[3]};
        *(uint4*)(outp + 16) = (uint4){r[4], r[5], r[6], r[7]};
    }
}

extern "C" void kernel_launch(void* const* d_in, const int* in_sizes, int n_in,
                              void* d_out, int out_size, void* d_ws, size_t ws_size,
                              hipStream_t stream) {
    const float* x    = (const float*)d_in[0];
    const int*   src  = (const int*)d_in[1];
    const int*   dst  = (const int*)d_in[2];
    const float* w_in = (const float*)d_in[3];
    const float* b_in = (const float*)d_in[4];
    const float* w_au = (const float*)d_in[5];
    const float* b_au = (const float*)d_in[6];
    const float* w_av = (const float*)d_in[7];
    const float* w1   = (const float*)d_in[8];
    const float* b1   = (const float*)d_in[9];
    const float* w2   = (const float*)d_in[10];
    const float* b2   = (const float*)d_in[11];
    const int N = in_sizes[0] / DIM;
    const int E = in_sizes[1];
    const int K = (N + BK - 1) / BK;      // buckets (<=1024 for N<=131072)
    const int B = (E + CH - 1) / CH;      // bucketing blocks

    // workspace ~65.1 MB
    char* p = (char*)d_ws;
    int*  deg    = (int*)p;  p += (size_t)N * 4;          //  0.4 MB
    int*  rowptr = (int*)p;  p += (size_t)N * 4;          //  0.4 MB
    int*  esrc   = (int*)p;  p += (size_t)E * 4;          //  6.4 MB
    bf16* h      = (bf16*)p; p += (size_t)N * DIM * 2;    // 25.6 MB head-major
    float* au    = (float*)p; p += (size_t)N * NH * 4;    //  3.2 MB
    float* av    = (float*)p; p += (size_t)N * NH * 4;    //  3.2 MB
    unsigned short* w_in_b = (unsigned short*)p; p += 128 * 128 * 2;   // 32 KB bf16 wt-layout
    unsigned short* w1_b   = (unsigned short*)p; p += 128 * 128 * 2;   // 32 KB (PERM applied)
    unsigned short* w2_b   = (unsigned short*)p; p += 128 * 128 * 2;   // 32 KB
    unsigned short* wc_b   = (unsigned short*)p; p += 16 * 128 * 2;    //  4 KB (PERM applied)
    bf16* agg    = (bf16*)p;  p += (size_t)N * DIM * 2;   // 25.6 MB head-major
    // build-time scratch overlaid into agg (dead until agg_csr runs):
    unsigned* packed = (unsigned*)agg;                          // E*4 = 6.4 MB
    int* mat   = (int*)((char*)agg + (size_t)E * 4);            // K*B*4 ~ 1.2 MB
    int* btot  = mat + (size_t)K * B;                           // K*4
    int* bbase = btot + K;                                      // K*4

    const int row_blocks = (N + 127) / 128;

    preconv_kernel<<<13, 256, 0, stream>>>(w_in, w1, w2, w_au, w_av, w_in_b, w1_b, w2_b, wc_b);

    gemm_in_attn_kernel<<<row_blocks, 512, 0, stream>>>(x, w_in_b, b_in, wc_b, b_au, h, au, av, N);

    bucket_count_kernel<<<B, 256, 0, stream>>>(dst, mat, E, K, B);
    scan_bucket_kernel<<<K, 64, 0, stream>>>(mat, btot, B);
    scan_total_kernel<<<1, 64, 0, stream>>>(btot, bbase, K);
    bucket_scatter_kernel<<<B, 256, 0, stream>>>(src, dst, mat, bbase, packed, E, K, B);
    bucket_csr_kernel<<<K, 256, 0, stream>>>(packed, bbase, btot, rowptr, deg, esrc, N);

    agg_csr_kernel<<<(N + 3) / 4, 256, 0, stream>>>(rowptr, deg, esrc, au, av, h, agg, N);

    ff_kernel<<<row_blocks, 512, 0, stream>>>(agg, w1_b, b1, w2_b, b2, (float*)d_out, N);
}

// Round 10
// 295.610 us; speedup vs baseline: 1.2760x; 1.2760x over previous
//
#include <hip/hip_runtime.h>
#include <hip/hip_bf16.h>
#include <stdint.h>

#define DIM 128
#define NH 8
#define CH 4096          // edges per bucketing block
#define BK 128           // nodes per bucket (K = ceil(N/128) <= 1024 for N <= 131072)
#define LS 136           // LDS row stride in shorts: 272B rows -> 16B-aligned b128; reads 2-way (free)
#define EBUF 4096        // per-bucket edge staging (mean 2048, sd ~45 for uniform dst)

using bf16 = __hip_bfloat16;
typedef __attribute__((ext_vector_type(8))) short short8;
typedef __attribute__((ext_vector_type(4))) float floatx4;

// head-major permutation: orig dim d -> pos(d) = (d&7)*16 + (d>>3)
// inverse: position kt -> orig(kt) = (kt&15)*8 + (kt>>4)

__device__ inline float bf2f(unsigned short b) {
    return __uint_as_float(((unsigned)b) << 16);
}
__device__ inline unsigned short f2bf(float f) {
    unsigned u = __float_as_uint(f);
    u += 0x7FFFu + ((u >> 16) & 1u);   // RNE
    return (unsigned short)(u >> 16);
}

__device__ inline float gelu_tanh(float x) {
    float x3 = x * x * x;
    float u = 0.7978845608028654f * (x + 0.044715f * x3);
    float e = __expf(2.f * u);
    float t = 1.f - 2.f / (e + 1.f);   // tanh(u), safe at +/-inf
    return 0.5f * x * (1.f + t);
}

// ============ fused: bucket histogram (blocks 0..B-1) + weight preconv (blocks B..B+12) ============
__launch_bounds__(256)
__global__ void count_pre_kernel(const int* __restrict__ dst, int* __restrict__ mat,
                                 int E, int K, int B,
                                 const float* __restrict__ w_in, const float* __restrict__ w1,
                                 const float* __restrict__ w2, const float* __restrict__ w_au,
                                 const float* __restrict__ w_av,
                                 unsigned short* __restrict__ w_in_b, unsigned short* __restrict__ w1_b,
                                 unsigned short* __restrict__ w2_b, unsigned short* __restrict__ wc_b) {
    __shared__ int cnt[1024];
    const int b = blockIdx.x, tid = threadIdx.x;
    if (b < B) {
        for (int k = tid; k < K; k += 256) cnt[k] = 0;
        __syncthreads();
        const int base = b * CH, end = min(base + CH, E);
        for (int i = base + tid; i < end; i += 256)
            atomicAdd(&cnt[dst[i] >> 7], 1);
        __syncthreads();
        for (int k = tid; k < K; k += 256) mat[(size_t)k * B + b] = cnt[k];
    } else {
        int pb = b - B;
        if (pb < 12) {
            const int m = pb >> 2, qtr = pb & 3;
            const float* W = m == 0 ? w_in : (m == 1 ? w1 : w2);
            unsigned short* O = m == 0 ? w_in_b : (m == 1 ? w1_b : w2_b);
            const bool perm = (m == 1);
            #pragma unroll
            for (int i = 0; i < 16; ++i) {
                int o = qtr * 4096 + tid + i * 256;   // o = n*128 + k
                int k = o & 127, n = o >> 7;
                int krow = perm ? ((k & 15) * 8 + (k >> 4)) : k;
                O[o] = f2bf(W[krow * 128 + n]);
            }
        } else {
            #pragma unroll
            for (int i = 0; i < 8; ++i) {
                int o = tid + i * 256;                // o = j*128 + kt
                int j = o >> 7, kt = o & 127;
                int ko = (kt & 15) * 8 + (kt >> 4);
                float v = (j < 8) ? w_au[ko * 8 + j] : w_av[ko * 8 + (j - 8)];
                wc_b[o] = f2bf(v);
            }
        }
    }
}

// vector stage: 2048 short8-groups (128x128 bf16) with 512 threads; all b128, coalesced.
__device__ __forceinline__ void stage_pre(unsigned short* wt, const unsigned short* __restrict__ pre,
                                          int tid) {
    #pragma unroll
    for (int i = 0; i < 4; ++i) {
        int g = tid + i * 512;                    // 0..2047: n = g>>4, blk = g&15
        short8 v = *(const short8*)(pre + g * 8);
        *(short8*)(wt + (g >> 4) * LS + (g & 15) * 8) = v;
    }
}

// ============ fused: h = x@w_in + b_in (head-major bf16) ; au/av via MFMA ============
__launch_bounds__(512)
__global__ void gemm_in_attn_kernel(const float* __restrict__ x, const unsigned short* __restrict__ w_in_b,
                                    const float* __restrict__ b_in,
                                    const unsigned short* __restrict__ wc_b, const float* __restrict__ b_au,
                                    bf16* __restrict__ h, float* __restrict__ au,
                                    float* __restrict__ av, int M) {
    __shared__ __align__(16) unsigned short wt[128 * LS];  // weights; then reused as h tile
    __shared__ __align__(16) unsigned short wc[16 * LS];
    const int tid = threadIdx.x;

    stage_pre(wt, w_in_b, tid);
    {   // wc: 512 x 4 shorts
        int j = tid >> 5, kt4 = (tid & 31) * 4;
        const unsigned* s = (const unsigned*)(wc_b + j * 128 + kt4);
        unsigned* d = (unsigned*)(wc + j * LS + kt4);
        d[0] = s[0]; d[1] = s[1];
    }
    __syncthreads();

    const int wave = tid >> 6;
    const int lane = tid & 63;
    const int l15 = lane & 15;
    const int q = lane >> 4;
    const int rowbase = blockIdx.x * 128 + wave * 16;
    const int rowA = min(rowbase + l15, M - 1);

    floatx4 acc[8];
    #pragma unroll
    for (int c = 0; c < 8; ++c) acc[c] = (floatx4){0.f, 0.f, 0.f, 0.f};

    #pragma unroll
    for (int kk = 0; kk < 4; ++kk) {
        const float* ap = x + (size_t)rowA * 128 + kk * 32 + q * 8;
        floatx4 a0 = *(const floatx4*)ap;
        floatx4 a1 = *(const floatx4*)(ap + 4);
        union { short8 s; unsigned short u[8]; } cv;
        #pragma unroll
        for (int j = 0; j < 4; ++j) { cv.u[j] = f2bf(a0[j]); cv.u[4 + j] = f2bf(a1[j]); }
        short8 afrag = cv.s;
        #pragma unroll
        for (int c = 0; c < 8; ++c) {
            short8 bfrag = *(const short8*)(wt + (c * 16 + l15) * LS + kk * 32 + q * 8);
            acc[c] = __builtin_amdgcn_mfma_f32_16x16x32_bf16(afrag, bfrag, acc[c], 0, 0, 0);
        }
    }
    __syncthreads();   // all wt reads done -> reuse as 128-row h tile

    const int rl0 = wave * 16 + q * 4;     // local row in h tile
    #pragma unroll
    for (int c = 0; c < 8; ++c) {
        int col = c * 16 + l15;
        int colw = (col & 7) * 16 + (col >> 3);   // head-major position
        float b = b_in[col];
        #pragma unroll
        for (int r = 0; r < 4; ++r)
            wt[(rl0 + r) * LS + colw] = f2bf(acc[c][r] + b);
    }
    __syncthreads();

    // coalesced h write from LDS tile (b128)
    const int blk0 = blockIdx.x * 128;
    #pragma unroll
    for (int i = 0; i < 4; ++i) {
        int g = tid + i * 512;                 // row = g>>4, blk = g&15
        int row = g >> 4;
        if (blk0 + row < M) {
            short8 v = *(const short8*)(wt + row * LS + (g & 15) * 8);
            *(short8*)((unsigned short*)h + (size_t)(blk0 + row) * 128 + (g & 15) * 8) = v;
        }
    }

    // au/av: one MFMA chain against wc (own-wave rows of wt)
    floatx4 acc2 = (floatx4){0.f, 0.f, 0.f, 0.f};
    #pragma unroll
    for (int kk = 0; kk < 4; ++kk) {
        short8 af = *(const short8*)(wt + (wave * 16 + l15) * LS + kk * 32 + q * 8);
        short8 bf = *(const short8*)(wc + l15 * LS + kk * 32 + q * 8);
        acc2 = __builtin_amdgcn_mfma_f32_16x16x32_bf16(af, bf, acc2, 0, 0, 0);
    }
    {
        const int row0 = rowbase + q * 4;
        int col = l15;
        #pragma unroll
        for (int r = 0; r < 4; ++r) {
            int rr = row0 + r;
            if (rr < M) {
                if (col < 8) au[(size_t)rr * 8 + col] = acc2[r] + b_au[col];
                else         av[(size_t)rr * 8 + (col - 8)] = acc2[r];
            }
        }
    }
}

// ============ fused FF: out = gelu(A@w1 + b1) @ w2 + b2 (A head-major bf16) ============
__launch_bounds__(512)
__global__ void ff_kernel(const bf16* __restrict__ A, const unsigned short* __restrict__ w1_b,
                          const float* __restrict__ b1, const unsigned short* __restrict__ w2_b,
                          const float* __restrict__ b2, float* __restrict__ out, int M) {
    __shared__ __align__(16) unsigned short wt[128 * LS];
    __shared__ __align__(16) unsigned short ht[128 * LS];
    const int tid = threadIdx.x;

    stage_pre(wt, w1_b, tid);
    __syncthreads();

    const int wave = tid >> 6;
    const int lane = tid & 63;
    const int l15 = lane & 15;
    const int q = lane >> 4;
    const int rowbase = blockIdx.x * 128 + wave * 16;
    const int rowA = min(rowbase + l15, M - 1);

    floatx4 acc[8];
    #pragma unroll
    for (int c = 0; c < 8; ++c) acc[c] = (floatx4){0.f, 0.f, 0.f, 0.f};

    #pragma unroll
    for (int kk = 0; kk < 4; ++kk) {
        short8 afrag = *(const short8*)((const unsigned short*)A + (size_t)rowA * 128 + kk * 32 + q * 8);
        #pragma unroll
        for (int c = 0; c < 8; ++c) {
            short8 bfrag = *(const short8*)(wt + (c * 16 + l15) * LS + kk * 32 + q * 8);
            acc[c] = __builtin_amdgcn_mfma_f32_16x16x32_bf16(afrag, bfrag, acc[c], 0, 0, 0);
        }
    }
    __syncthreads();   // wt reads done

    stage_pre(wt, w2_b, tid);     // re-stage w2 (cheap vector copy)
    const int rl0 = wave * 16 + q * 4;
    #pragma unroll
    for (int c = 0; c < 8; ++c) {
        int col = c * 16 + l15;
        float b = b1[col];
        #pragma unroll
        for (int r = 0; r < 4; ++r)
            ht[(rl0 + r) * LS + col] = f2bf(gelu_tanh(acc[c][r] + b));
    }
    __syncthreads();

    floatx4 acc2[8];
    #pragma unroll
    for (int c = 0; c < 8; ++c) acc2[c] = (floatx4){0.f, 0.f, 0.f, 0.f};
    #pragma unroll
    for (int kk = 0; kk < 4; ++kk) {
        short8 af = *(const short8*)(ht + (wave * 16 + l15) * LS + kk * 32 + q * 8);
        #pragma unroll
        for (int c = 0; c < 8; ++c) {
            short8 bfrag = *(const short8*)(wt + (c * 16 + l15) * LS + kk * 32 + q * 8);
            acc2[c] = __builtin_amdgcn_mfma_f32_16x16x32_bf16(af, bfrag, acc2[c], 0, 0, 0);
        }
    }

    const int row0 = rowbase + q * 4;
    #pragma unroll
    for (int c = 0; c < 8; ++c) {
        int col = c * 16 + l15;
        float b = b2[col];
        #pragma unroll
        for (int r = 0; r < 4; ++r) {
            int rr = row0 + r;
            if (rr < M) out[(size_t)rr * 128 + col] = acc2[c][r] + b;
        }
    }
}

// ======================= atomic-free CSR build (LDS multisplit) =======================

// exclusive scan along b for each bucket row; mat[k][b] -> exclusive, btot[k] = total.
__launch_bounds__(64)
__global__ void scan_bucket_kernel(int* __restrict__ mat, int* __restrict__ btot, int B) {
    const int k = blockIdx.x;
    const int lane = threadIdx.x;
    const size_t base = (size_t)k * B;
    int carry = 0;
    for (int i0 = 0; i0 < B; i0 += 64) {
        int idx = i0 + lane;
        int v = (idx < B) ? mat[base + idx] : 0;
        int incl = v;
        #pragma unroll
        for (int off = 1; off < 64; off <<= 1) {
            int y = __shfl_up(incl, off);
            if (lane >= off) incl += y;
        }
        int tot = __shfl(incl, 63);
        if (idx < B) mat[base + idx] = carry + incl - v;
        carry += tot;
    }
    if (lane == 0) btot[k] = carry;
}

__launch_bounds__(64)
__global__ void scan_total_kernel(const int* __restrict__ btot, int* __restrict__ bbase, int K) {
    const int lane = threadIdx.x;
    int carry = 0;
    for (int i0 = 0; i0 < K; i0 += 64) {
        int idx = i0 + lane;
        int v = (idx < K) ? btot[idx] : 0;
        int incl = v;
        #pragma unroll
        for (int off = 1; off < 64; off <<= 1) {
            int y = __shfl_up(incl, off);
            if (lane >= off) incl += y;
        }
        int tot = __shfl(incl, 63);
        if (idx < K) bbase[idx] = carry + incl - v;
        carry += tot;
    }
}

// CHUNK-LOCAL bucket sort: every global write is block-exclusive (full-line, no
// cross-XCD line sharing). Writes packed[b*CH + localpos] sorted by bucket, plus
// lofs[b*K+k] = chunk-local exclusive offset of bucket k.
__launch_bounds__(256)
__global__ void bucket_scatter_kernel(const int* __restrict__ src, const int* __restrict__ dst,
                                      int* __restrict__ lofs, unsigned* __restrict__ packed,
                                      int E, int K, int B) {
    __shared__ int hist[1024];
    __shared__ int cur[1024];
    __shared__ int wsum[4];
    const int b = blockIdx.x, tid = threadIdx.x;
    for (int k = tid; k < 1024; k += 256) hist[k] = 0;
    __syncthreads();
    const int base = b * CH, end = min(base + CH, E);
    for (int i = base + tid; i < end; i += 256)
        atomicAdd(&hist[dst[i] >> 7], 1);
    __syncthreads();
    // exclusive scan of hist[0..1024) (slots >= K are zero)
    int v[4]; int t = 0;
    #pragma unroll
    for (int j = 0; j < 4; ++j) { int x = hist[tid * 4 + j]; v[j] = t; t += x; }
    const int lane = tid & 63, wv = tid >> 6;
    int incl = t;
    #pragma unroll
    for (int off = 1; off < 64; off <<= 1) {
        int y = __shfl_up(incl, off);
        if (lane >= off) incl += y;
    }
    if (lane == 63) wsum[wv] = incl;
    __syncthreads();
    int woff = 0;
    #pragma unroll
    for (int w = 0; w < 4; ++w) if (w < wv) woff += wsum[w];
    int texcl = woff + incl - t;
    #pragma unroll
    for (int j = 0; j < 4; ++j) {
        int k = tid * 4 + j;
        int e = texcl + v[j];
        cur[k] = e;
        if (k < K) lofs[(size_t)b * K + k] = e;
    }
    __syncthreads();
    for (int i = base + tid; i < end; i += 256) {
        int d = dst[i], s = src[i];
        int pos = atomicAdd(&cur[d >> 7], 1);
        packed[(size_t)b * CH + pos] = (unsigned)s | ((unsigned)(d & 127) << 20);
    }
}

// per-bucket: gather the bucket's runs from all chunks into LDS, then group by node.
// esrc writes are a contiguous block-exclusive segment (full-line writes).
__launch_bounds__(256)
__global__ void bucket_csr_kernel(const unsigned* __restrict__ packed, const int* __restrict__ lofs,
                                  const int* __restrict__ mat,
                                  const int* __restrict__ bbase, const int* __restrict__ btot,
                                  int* __restrict__ rowptr, int* __restrict__ deg,
                                  int* __restrict__ esrc, int N, int E, int K, int B) {
    __shared__ unsigned ebuf[EBUF];
    __shared__ int hist[128], cur[128];
    __shared__ int wtot;
    const int k = blockIdx.x, tid = threadIdx.x;
    const int start = bbase[k];
    const int cnt = btot[k];

    // gather runs: run b lives at packed[b*CH + lo .. hi), lands at ebuf[mat[k][b]..]
    for (int b = tid; b < B; b += 256) {
        int lo = lofs[(size_t)b * K + k];
        int chunk_len = min(CH, E - b * CH);
        int hi = (k + 1 < K) ? lofs[(size_t)b * K + k + 1] : chunk_len;
        int dbase = mat[(size_t)k * B + b];
        const unsigned* sp = packed + (size_t)b * CH;
        for (int j = lo; j < hi; ++j) ebuf[dbase + (j - lo)] = sp[j];
    }
    if (tid < 128) hist[tid] = 0;
    __syncthreads();

    for (int i = tid; i < cnt; i += 256)
        atomicAdd(&hist[ebuf[i] >> 20], 1);
    __syncthreads();

    const int lane = tid & 63;
    int v = (tid < 128) ? hist[tid] : 0;
    int incl = v;
    #pragma unroll
    for (int off = 1; off < 64; off <<= 1) {
        int y = __shfl_up(incl, off);
        if (lane >= off) incl += y;
    }
    if (tid == 63) wtot = incl;       // total of nodes 0..63
    __syncthreads();
    int excl = incl - v + ((tid >= 64 && tid < 128) ? wtot : 0);
    if (tid < 128) {
        int n = k * BK + tid;
        if (n < N) { rowptr[n] = start + excl; deg[n] = v; }
        cur[tid] = excl;
    }
    __syncthreads();

    for (int i = tid; i < cnt; i += 256) {
        unsigned p = ebuf[i];
        int pos = atomicAdd(&cur[p >> 20], 1);
        esrc[start + pos] = (int)(p & 0xFFFFFu);
    }
}

// ======================= fused softmax aggregation (CSR, head-major) =======================
// One wave per node, 8 edges in flight: 8 lanes per edge, lane owns ONE full head
// (16 contiguous head-major dims, 2 x b128 loads). 8 exps per edge.
// No max-subtraction: scores = leaky(au+av) bounded ~|8| -> exp <= ~3e3, safe.

__device__ __forceinline__ void unpack8fma(uint4 w, float p, float* o) {
    o[0] = fmaf(p, __uint_as_float(w.x << 16), o[0]);
    o[1] = fmaf(p, __uint_as_float(w.x & 0xFFFF0000u), o[1]);
    o[2] = fmaf(p, __uint_as_float(w.y << 16), o[2]);
    o[3] = fmaf(p, __uint_as_float(w.y & 0xFFFF0000u), o[3]);
    o[4] = fmaf(p, __uint_as_float(w.z << 16), o[4]);
    o[5] = fmaf(p, __uint_as_float(w.z & 0xFFFF0000u), o[5]);
    o[6] = fmaf(p, __uint_as_float(w.w << 16), o[6]);
    o[7] = fmaf(p, __uint_as_float(w.w & 0xFFFF0000u), o[7]);
}

template <bool MASKED>
__device__ __forceinline__ void do8e(const int* __restrict__ ep, int i, int nd,
                                     int e, int head, int d0b,
                                     const float* __restrict__ au,
                                     const char* __restrict__ hpb,
                                     float avh, float& l, float* o) {
    int idx = i + e;
    int s;
    float m = 1.f;
    if constexpr (MASKED) {
        s = ep[min(idx, nd - 1)];
        m = idx < nd ? 1.f : 0.f;
    } else {
        s = ep[idx];
    }
    float a = au[(s << 3) + head];
    size_t off = ((size_t)(unsigned)s) << 8;        // 256 B per node row
    uint4 w0 = *(const uint4*)(hpb + off + d0b);
    uint4 w1 = *(const uint4*)(hpb + off + d0b + 16);
    float x = a + avh;
    x = fmaxf(x, 0.2f * x);          // LeakyReLU(0.2)
    float p = __expf(x);
    if constexpr (MASKED) p *= m;
    l += p;
    unpack8fma(w0, p, o);
    unpack8fma(w1, p, o + 8);
}

__launch_bounds__(256)
__global__ void agg_csr_kernel(const int* __restrict__ rowptr, const int* __restrict__ deg,
                               const int* __restrict__ esrc,
                               const float* __restrict__ au, const float* __restrict__ av,
                               const bf16* __restrict__ h, bf16* __restrict__ agg, int N) {
    const int node = (blockIdx.x * 256 + threadIdx.x) >> 6;
    if (node >= N) return;
    const int lane = threadIdx.x & 63;
    const int e = lane >> 3;          // which edge of the 8-batch
    const int head = lane & 7;        // lane's single head
    const int d0b = head * 32;        // byte offset of its 16 head-major dims
    const char* hpb = (const char*)h;
    const int nd = deg[node];
    const int start = rowptr[node];
    const float avh = av[((size_t)node << 3) + head];
    const int* ep = esrc + start;

    float l0 = 0.f;
    float o[16];
    #pragma unroll
    for (int j = 0; j < 16; ++j) o[j] = 0.f;

    int i = 0;
    for (; i + 16 <= nd; i += 16) {
        do8e<false>(ep, i, nd, e, head, d0b, au, hpb, avh, l0, o);
        do8e<false>(ep, i + 8, nd, e, head, d0b, au, hpb, avh, l0, o);
    }
    if (i + 8 <= nd) { do8e<false>(ep, i, nd, e, head, d0b, au, hpb, avh, l0, o); i += 8; }
    if (i < nd) do8e<true>(ep, i, nd, e, head, d0b, au, hpb, avh, l0, o);

    // sum the 8 edge-groups (lanes l, l^8, l^16, ..., l^56 own the same dims)
    #pragma unroll
    for (int j = 0; j < 16; ++j) {
        o[j] += __shfl_xor(o[j], 8);
        o[j] += __shfl_xor(o[j], 16);
        o[j] += __shfl_xor(o[j], 32);
    }
    l0 += __shfl_xor(l0, 8);
    l0 += __shfl_xor(l0, 16);
    l0 += __shfl_xor(l0, 32);

    if (lane < 8) {
        float inv = l0 > 0.f ? 1.f / l0 : 0.f;   // deg-0 -> 0 (matches segment_sum)
        unsigned r[8];
        #pragma unroll
        for (int j = 0; j < 8; ++j)
            r[j] = ((unsigned)f2bf(o[2 * j + 1] * inv) << 16) | (unsigned)f2bf(o[2 * j] * inv);
        char* outp = (char*)agg + ((size_t)node << 8) + lane * 32;
        *(uint4*)outp = (uint4){r[0], r[1], r[2], r[3]};
        *(uint4*)(outp + 16) = (uint4){r[4], r[5], r[6], r[7]};
    }
}

extern "C" void kernel_launch(void* const* d_in, const int* in_sizes, int n_in,
                              void* d_out, int out_size, void* d_ws, size_t ws_size,
                              hipStream_t stream) {
    const float* x    = (const float*)d_in[0];
    const int*   src  = (const int*)d_in[1];
    const int*   dst  = (const int*)d_in[2];
    const float* w_in = (const float*)d_in[3];
    const float* b_in = (const float*)d_in[4];
    const float* w_au = (const float*)d_in[5];
    const float* b_au = (const float*)d_in[6];
    const float* w_av = (const float*)d_in[7];
    const float* w1   = (const float*)d_in[8];
    const float* b1   = (const float*)d_in[9];
    const float* w2   = (const float*)d_in[10];
    const float* b2   = (const float*)d_in[11];
    const int N = in_sizes[0] / DIM;
    const int E = in_sizes[1];
    const int K = (N + BK - 1) / BK;      // buckets (<=1024 for N<=131072)
    const int B = (E + CH - 1) / CH;      // bucketing blocks

    // workspace ~65.1 MB
    char* p = (char*)d_ws;
    int*  deg    = (int*)p;  p += (size_t)N * 4;          //  0.4 MB
    int*  rowptr = (int*)p;  p += (size_t)N * 4;          //  0.4 MB
    int*  esrc   = (int*)p;  p += (size_t)E * 4;          //  6.4 MB
    bf16* h      = (bf16*)p; p += (size_t)N * DIM * 2;    // 25.6 MB head-major
    float* au    = (float*)p; p += (size_t)N * NH * 4;    //  3.2 MB
    float* av    = (float*)p; p += (size_t)N * NH * 4;    //  3.2 MB
    unsigned short* w_in_b = (unsigned short*)p; p += 128 * 128 * 2;   // 32 KB bf16 wt-layout
    unsigned short* w1_b   = (unsigned short*)p; p += 128 * 128 * 2;   // 32 KB (PERM applied)
    unsigned short* w2_b   = (unsigned short*)p; p += 128 * 128 * 2;   // 32 KB
    unsigned short* wc_b   = (unsigned short*)p; p += 16 * 128 * 2;    //  4 KB (PERM applied)
    bf16* agg    = (bf16*)p;  p += (size_t)N * DIM * 2;   // 25.6 MB head-major
    // build-time scratch overlaid into agg (dead until agg_csr runs):
    unsigned* packed = (unsigned*)agg;                          // B*CH*4 ~ 6.4 MB
    int* mat   = (int*)((char*)agg + (size_t)B * CH * 4);       // K*B*4 ~ 1.25 MB
    int* btot  = mat + (size_t)K * B;                           // K*4
    int* bbase = btot + K;                                      // K*4
    int* lofs  = bbase + K;                                     // B*K*4 ~ 1.25 MB

    const int row_blocks = (N + 127) / 128;

    count_pre_kernel<<<B + 13, 256, 0, stream>>>(dst, mat, E, K, B,
                                                 w_in, w1, w2, w_au, w_av,
                                                 w_in_b, w1_b, w2_b, wc_b);

    gemm_in_attn_kernel<<<row_blocks, 512, 0, stream>>>(x, w_in_b, b_in, wc_b, b_au, h, au, av, N);

    scan_bucket_kernel<<<K, 64, 0, stream>>>(mat, btot, B);
    scan_total_kernel<<<1, 64, 0, stream>>>(btot, bbase, K);
    bucket_scatter_kernel<<<B, 256, 0, stream>>>(src, dst, lofs, packed, E, K, B);
    bucket_csr_kernel<<<K, 256, 0, stream>>>(packed, lofs, mat, bbase, btot,
                                             rowptr, deg, esrc, N, E, K, B);

    agg_csr_kernel<<<(N + 3) / 4, 256, 0, stream>>>(rowptr, deg, esrc, au, av, h, agg, N);

    ff_kernel<<<row_blocks, 512, 0, stream>>>(agg, w1_b, b1, w2_b, b2, (float*)d_out, N);
}

// Round 11
// 278.779 us; speedup vs baseline: 1.3530x; 1.0604x over previous
//
#include <hip/hip_runtime.h>
#include <hip/hip_bf16.h>
#include <stdint.h>

#define DIM 128
#define NH 8
#define CH 4096          // edges per bucketing block
#define BK 128           // nodes per bucket (K = ceil(N/128) <= 1024 for N <= 131072)
#define LS 136           // LDS row stride in shorts: 272B rows -> 16B-aligned b128; reads 2-way (free)
#define EBUF 4096        // per-bucket edge staging (mean 2048, sd ~45 for uniform dst)

using bf16 = __hip_bfloat16;
typedef __attribute__((ext_vector_type(8))) short short8;
typedef __attribute__((ext_vector_type(4))) float floatx4;

// head-major permutation: orig dim d -> pos(d) = (d&7)*16 + (d>>3)
// inverse: position kt -> orig(kt) = (kt&15)*8 + (kt>>4)

__device__ inline float bf2f(unsigned short b) {
    return __uint_as_float(((unsigned)b) << 16);
}
__device__ inline unsigned short f2bf(float f) {
    unsigned u = __float_as_uint(f);
    u += 0x7FFFu + ((u >> 16) & 1u);   // RNE
    return (unsigned short)(u >> 16);
}

__device__ inline float gelu_tanh(float x) {
    float x3 = x * x * x;
    float u = 0.7978845608028654f * (x + 0.044715f * x3);
    float e = __expf(2.f * u);
    float t = 1.f - 2.f / (e + 1.f);   // tanh(u), safe at +/-inf
    return 0.5f * x * (1.f + t);
}

// ============ K1: chunk-local bucket sort (+ mat emit) fused with weight preconv ============
// blocks [0,B): sort chunk b by bucket; write packed (block-exclusive), lofs[b][k],
//               mat[b][k] (B-major -> contiguous block-exclusive lines).
// blocks [B,B+12): weight quarters. block B+12: wc + total=0.
__launch_bounds__(256)
__global__ void scatter_pre_kernel(const int* __restrict__ src, const int* __restrict__ dst,
                                   int* __restrict__ lofs, int* __restrict__ mat,
                                   unsigned* __restrict__ packed, int* __restrict__ total,
                                   int E, int K, int B,
                                   const float* __restrict__ w_in, const float* __restrict__ w1,
                                   const float* __restrict__ w2, const float* __restrict__ w_au,
                                   const float* __restrict__ w_av,
                                   unsigned short* __restrict__ w_in_b, unsigned short* __restrict__ w1_b,
                                   unsigned short* __restrict__ w2_b, unsigned short* __restrict__ wc_b) {
    __shared__ int hist[1024];
    __shared__ int cur[1024];
    __shared__ int wsum[4];
    const int b = blockIdx.x, tid = threadIdx.x;
    if (b < B) {
        for (int k = tid; k < 1024; k += 256) hist[k] = 0;
        __syncthreads();
        const int base = b * CH, end = min(base + CH, E);
        for (int i = base + tid; i < end; i += 256)
            atomicAdd(&hist[dst[i] >> 7], 1);
        __syncthreads();
        int v[4]; int t = 0;
        #pragma unroll
        for (int j = 0; j < 4; ++j) { int x = hist[tid * 4 + j]; v[j] = t; t += x; }
        const int lane = tid & 63, wv = tid >> 6;
        int incl = t;
        #pragma unroll
        for (int off = 1; off < 64; off <<= 1) {
            int y = __shfl_up(incl, off);
            if (lane >= off) incl += y;
        }
        if (lane == 63) wsum[wv] = incl;
        __syncthreads();
        int woff = 0;
        #pragma unroll
        for (int w = 0; w < 4; ++w) if (w < wv) woff += wsum[w];
        int texcl = woff + incl - t;
        #pragma unroll
        for (int j = 0; j < 4; ++j) {
            int k = tid * 4 + j;
            int e = texcl + v[j];
            cur[k] = e;
            if (k < K) {
                lofs[(size_t)b * K + k] = e;            // contiguous per block
                mat[(size_t)b * 1024 + k] = hist[k];    // B-major: contiguous per block
            }
        }
        __syncthreads();
        for (int i = base + tid; i < end; i += 256) {
            int d = dst[i], s = src[i];
            int pos = atomicAdd(&cur[d >> 7], 1);
            packed[(size_t)b * CH + pos] = (unsigned)s | ((unsigned)(d & 127) << 20);
        }
    } else {
        int pb = b - B;
        if (pb < 12) {
            const int m = pb >> 2, qtr = pb & 3;
            const float* W = m == 0 ? w_in : (m == 1 ? w1 : w2);
            unsigned short* O = m == 0 ? w_in_b : (m == 1 ? w1_b : w2_b);
            const bool perm = (m == 1);
            #pragma unroll
            for (int i = 0; i < 16; ++i) {
                int o = qtr * 4096 + tid + i * 256;   // o = n*128 + k
                int k = o & 127, n = o >> 7;
                int krow = perm ? ((k & 15) * 8 + (k >> 4)) : k;
                O[o] = f2bf(W[krow * 128 + n]);
            }
        } else {
            #pragma unroll
            for (int i = 0; i < 8; ++i) {
                int o = tid + i * 256;                // o = j*128 + kt
                int j = o >> 7, kt = o & 127;
                int ko = (kt & 15) * 8 + (kt >> 4);
                float v = (j < 8) ? w_au[ko * 8 + j] : w_av[ko * 8 + (j - 8)];
                wc_b[o] = f2bf(v);
            }
            if (tid == 0) total[0] = 0;
        }
    }
}

// vector stage: 2048 short8-groups (128x128 bf16) with 512 threads; all b128, coalesced.
__device__ __forceinline__ void stage_pre(unsigned short* wt, const unsigned short* __restrict__ pre,
                                          int tid) {
    #pragma unroll
    for (int i = 0; i < 4; ++i) {
        int g = tid + i * 512;                    // 0..2047: n = g>>4, blk = g&15
        short8 v = *(const short8*)(pre + g * 8);
        *(short8*)(wt + (g >> 4) * LS + (g & 15) * 8) = v;
    }
}

// ============ K2: gemm_in_attn (blocks [0,RB)) fused with per-bucket scan (blocks [RB,RB+K)) ====
// Scan block k: exclusive-scan mat[.][k] across chunks -> matx[k][.] (K-major, contiguous
// per block); bucket base via ONE device atomicAdd (CSR segments need no global order).
__launch_bounds__(512)
__global__ void gia_scan_kernel(const float* __restrict__ x, const unsigned short* __restrict__ w_in_b,
                                const float* __restrict__ b_in,
                                const unsigned short* __restrict__ wc_b, const float* __restrict__ b_au,
                                bf16* __restrict__ h, float* __restrict__ au,
                                float* __restrict__ av, int M, int RB,
                                const int* __restrict__ mat, int* __restrict__ matx,
                                int* __restrict__ btot, int* __restrict__ bbase,
                                int* __restrict__ total, int K, int B) {
    __shared__ __align__(16) unsigned short wt[128 * LS];  // gia: weights then h tile
    __shared__ __align__(16) unsigned short wc[16 * LS];
    __shared__ int sscr[8];
    const int tid = threadIdx.x;

    if ((int)blockIdx.x >= RB) {
        // ---- scan branch ----
        const int k = blockIdx.x - RB;
        int v = (tid < B) ? mat[(size_t)tid * 1024 + k] : 0;
        const int lane = tid & 63, wv = tid >> 6;
        int incl = v;
        #pragma unroll
        for (int off = 1; off < 64; off <<= 1) {
            int y = __shfl_up(incl, off);
            if (lane >= off) incl += y;
        }
        if (lane == 63) sscr[wv] = incl;
        __syncthreads();
        int woff = 0, tot = 0;
        #pragma unroll
        for (int w = 0; w < 8; ++w) { int s = sscr[w]; if (w < wv) woff += s; tot += s; }
        if (tid < B) matx[(size_t)k * B + tid] = woff + incl - v;
        if (tid == 0) { bbase[k] = atomicAdd(total, tot); btot[k] = tot; }
        return;
    }

    // ---- gemm_in_attn branch ----
    stage_pre(wt, w_in_b, tid);
    {   // wc: 512 x 4 shorts
        int j = tid >> 5, kt4 = (tid & 31) * 4;
        const unsigned* s = (const unsigned*)(wc_b + j * 128 + kt4);
        unsigned* d = (unsigned*)(wc + j * LS + kt4);
        d[0] = s[0]; d[1] = s[1];
    }
    __syncthreads();

    const int wave = tid >> 6;
    const int lane = tid & 63;
    const int l15 = lane & 15;
    const int q = lane >> 4;
    const int rowbase = blockIdx.x * 128 + wave * 16;
    const int rowA = min(rowbase + l15, M - 1);

    floatx4 acc[8];
    #pragma unroll
    for (int c = 0; c < 8; ++c) acc[c] = (floatx4){0.f, 0.f, 0.f, 0.f};

    #pragma unroll
    for (int kk = 0; kk < 4; ++kk) {
        const float* ap = x + (size_t)rowA * 128 + kk * 32 + q * 8;
        floatx4 a0 = *(const floatx4*)ap;
        floatx4 a1 = *(const floatx4*)(ap + 4);
        union { short8 s; unsigned short u[8]; } cv;
        #pragma unroll
        for (int j = 0; j < 4; ++j) { cv.u[j] = f2bf(a0[j]); cv.u[4 + j] = f2bf(a1[j]); }
        short8 afrag = cv.s;
        #pragma unroll
        for (int c = 0; c < 8; ++c) {
            short8 bfrag = *(const short8*)(wt + (c * 16 + l15) * LS + kk * 32 + q * 8);
            acc[c] = __builtin_amdgcn_mfma_f32_16x16x32_bf16(afrag, bfrag, acc[c], 0, 0, 0);
        }
    }
    __syncthreads();   // all wt reads done -> reuse as 128-row h tile

    const int rl0 = wave * 16 + q * 4;     // local row in h tile
    #pragma unroll
    for (int c = 0; c < 8; ++c) {
        int col = c * 16 + l15;
        int colw = (col & 7) * 16 + (col >> 3);   // head-major position
        float b = b_in[col];
        #pragma unroll
        for (int r = 0; r < 4; ++r)
            wt[(rl0 + r) * LS + colw] = f2bf(acc[c][r] + b);
    }
    __syncthreads();

    // coalesced h write from LDS tile (b128)
    const int blk0 = blockIdx.x * 128;
    #pragma unroll
    for (int i = 0; i < 4; ++i) {
        int g = tid + i * 512;                 // row = g>>4, blk = g&15
        int row = g >> 4;
        if (blk0 + row < M) {
            short8 v = *(const short8*)(wt + row * LS + (g & 15) * 8);
            *(short8*)((unsigned short*)h + (size_t)(blk0 + row) * 128 + (g & 15) * 8) = v;
        }
    }

    // au/av: one MFMA chain against wc (own-wave rows of wt)
    floatx4 acc2 = (floatx4){0.f, 0.f, 0.f, 0.f};
    #pragma unroll
    for (int kk = 0; kk < 4; ++kk) {
        short8 af = *(const short8*)(wt + (wave * 16 + l15) * LS + kk * 32 + q * 8);
        short8 bf = *(const short8*)(wc + l15 * LS + kk * 32 + q * 8);
        acc2 = __builtin_amdgcn_mfma_f32_16x16x32_bf16(af, bf, acc2, 0, 0, 0);
    }
    {
        const int row0 = rowbase + q * 4;
        int col = l15;
        #pragma unroll
        for (int r = 0; r < 4; ++r) {
            int rr = row0 + r;
            if (rr < M) {
                if (col < 8) au[(size_t)rr * 8 + col] = acc2[r] + b_au[col];
                else         av[(size_t)rr * 8 + (col - 8)] = acc2[r];
            }
        }
    }
}

// ============ fused FF: out = gelu(A@w1 + b1) @ w2 + b2 (A head-major bf16) ============
__launch_bounds__(512)
__global__ void ff_kernel(const bf16* __restrict__ A, const unsigned short* __restrict__ w1_b,
                          const float* __restrict__ b1, const unsigned short* __restrict__ w2_b,
                          const float* __restrict__ b2, float* __restrict__ out, int M) {
    __shared__ __align__(16) unsigned short wt[128 * LS];
    __shared__ __align__(16) unsigned short ht[128 * LS];
    const int tid = threadIdx.x;

    stage_pre(wt, w1_b, tid);
    __syncthreads();

    const int wave = tid >> 6;
    const int lane = tid & 63;
    const int l15 = lane & 15;
    const int q = lane >> 4;
    const int rowbase = blockIdx.x * 128 + wave * 16;
    const int rowA = min(rowbase + l15, M - 1);

    floatx4 acc[8];
    #pragma unroll
    for (int c = 0; c < 8; ++c) acc[c] = (floatx4){0.f, 0.f, 0.f, 0.f};

    #pragma unroll
    for (int kk = 0; kk < 4; ++kk) {
        short8 afrag = *(const short8*)((const unsigned short*)A + (size_t)rowA * 128 + kk * 32 + q * 8);
        #pragma unroll
        for (int c = 0; c < 8; ++c) {
            short8 bfrag = *(const short8*)(wt + (c * 16 + l15) * LS + kk * 32 + q * 8);
            acc[c] = __builtin_amdgcn_mfma_f32_16x16x32_bf16(afrag, bfrag, acc[c], 0, 0, 0);
        }
    }
    __syncthreads();   // wt reads done

    stage_pre(wt, w2_b, tid);     // re-stage w2 (cheap vector copy)
    const int rl0 = wave * 16 + q * 4;
    #pragma unroll
    for (int c = 0; c < 8; ++c) {
        int col = c * 16 + l15;
        float b = b1[col];
        #pragma unroll
        for (int r = 0; r < 4; ++r)
            ht[(rl0 + r) * LS + col] = f2bf(gelu_tanh(acc[c][r] + b));
    }
    __syncthreads();

    floatx4 acc2[8];
    #pragma unroll
    for (int c = 0; c < 8; ++c) acc2[c] = (floatx4){0.f, 0.f, 0.f, 0.f};
    #pragma unroll
    for (int kk = 0; kk < 4; ++kk) {
        short8 af = *(const short8*)(ht + (wave * 16 + l15) * LS + kk * 32 + q * 8);
        #pragma unroll
        for (int c = 0; c < 8; ++c) {
            short8 bfrag = *(const short8*)(wt + (c * 16 + l15) * LS + kk * 32 + q * 8);
            acc2[c] = __builtin_amdgcn_mfma_f32_16x16x32_bf16(af, bfrag, acc2[c], 0, 0, 0);
        }
    }

    const int row0 = rowbase + q * 4;
    #pragma unroll
    for (int c = 0; c < 8; ++c) {
        int col = c * 16 + l15;
        float b = b2[col];
        #pragma unroll
        for (int r = 0; r < 4; ++r) {
            int rr = row0 + r;
            if (rr < M) out[(size_t)rr * 128 + col] = acc2[c][r] + b;
        }
    }
}

// ============ K3: per-bucket CSR finalize (gather runs -> LDS -> group by node) ============
__launch_bounds__(256)
__global__ void bucket_csr_kernel(const unsigned* __restrict__ packed, const int* __restrict__ lofs,
                                  const int* __restrict__ matx,
                                  const int* __restrict__ bbase, const int* __restrict__ btot,
                                  int* __restrict__ rowptr, int* __restrict__ deg,
                                  int* __restrict__ esrc, int N, int E, int K, int B) {
    __shared__ unsigned ebuf[EBUF];
    __shared__ int hist[128], cur[128];
    __shared__ int wtot;
    const int k = blockIdx.x, tid = threadIdx.x;
    const int start = bbase[k];
    const int cnt = btot[k];

    // gather runs: run b lives at packed[b*CH + lo .. hi), lands at ebuf[matx[k][b]..]
    for (int b = tid; b < B; b += 256) {
        int lo = lofs[(size_t)b * K + k];
        int chunk_len = min(CH, E - b * CH);
        int hi = (k + 1 < K) ? lofs[(size_t)b * K + k + 1] : chunk_len;
        int dbase = matx[(size_t)k * B + b];
        const unsigned* sp = packed + (size_t)b * CH;
        for (int j = lo; j < hi; ++j) ebuf[dbase + (j - lo)] = sp[j];
    }
    if (tid < 128) hist[tid] = 0;
    __syncthreads();

    for (int i = tid; i < cnt; i += 256)
        atomicAdd(&hist[ebuf[i] >> 20], 1);
    __syncthreads();

    const int lane = tid & 63;
    int v = (tid < 128) ? hist[tid] : 0;
    int incl = v;
    #pragma unroll
    for (int off = 1; off < 64; off <<= 1) {
        int y = __shfl_up(incl, off);
        if (lane >= off) incl += y;
    }
    if (tid == 63) wtot = incl;       // total of nodes 0..63
    __syncthreads();
    int excl = incl - v + ((tid >= 64 && tid < 128) ? wtot : 0);
    if (tid < 128) {
        int n = k * BK + tid;
        if (n < N) { rowptr[n] = start + excl; deg[n] = v; }
        cur[tid] = excl;
    }
    __syncthreads();

    for (int i = tid; i < cnt; i += 256) {
        unsigned p = ebuf[i];
        int pos = atomicAdd(&cur[p >> 20], 1);
        esrc[start + pos] = (int)(p & 0xFFFFFu);
    }
}

// ======================= fused softmax aggregation (CSR, head-major) =======================
// One wave per node, 8 edges in flight: 8 lanes per edge, lane owns ONE full head
// (16 contiguous head-major dims, 2 x b128 loads). 8 exps per edge.
// No max-subtraction: scores = leaky(au+av) bounded ~|8| -> exp <= ~3e3, safe.

__device__ __forceinline__ void unpack8fma(uint4 w, float p, float* o) {
    o[0] = fmaf(p, __uint_as_float(w.x << 16), o[0]);
    o[1] = fmaf(p, __uint_as_float(w.x & 0xFFFF0000u), o[1]);
    o[2] = fmaf(p, __uint_as_float(w.y << 16), o[2]);
    o[3] = fmaf(p, __uint_as_float(w.y & 0xFFFF0000u), o[3]);
    o[4] = fmaf(p, __uint_as_float(w.z << 16), o[4]);
    o[5] = fmaf(p, __uint_as_float(w.z & 0xFFFF0000u), o[5]);
    o[6] = fmaf(p, __uint_as_float(w.w << 16), o[6]);
    o[7] = fmaf(p, __uint_as_float(w.w & 0xFFFF0000u), o[7]);
}

template <bool MASKED>
__device__ __forceinline__ void do8e(const int* __restrict__ ep, int i, int nd,
                                     int e, int head, int d0b,
                                     const float* __restrict__ au,
                                     const char* __restrict__ hpb,
                                     float avh, float& l, float* o) {
    int idx = i + e;
    int s;
    float m = 1.f;
    if constexpr (MASKED) {
        s = ep[min(idx, nd - 1)];
        m = idx < nd ? 1.f : 0.f;
    } else {
        s = ep[idx];
    }
    float a = au[(s << 3) + head];
    size_t off = ((size_t)(unsigned)s) << 8;        // 256 B per node row
    uint4 w0 = *(const uint4*)(hpb + off + d0b);
    uint4 w1 = *(const uint4*)(hpb + off + d0b + 16);
    float x = a + avh;
    x = fmaxf(x, 0.2f * x);          // LeakyReLU(0.2)
    float p = __expf(x);
    if constexpr (MASKED) p *= m;
    l += p;
    unpack8fma(w0, p, o);
    unpack8fma(w1, p, o + 8);
}

__launch_bounds__(256)
__global__ void agg_csr_kernel(const int* __restrict__ rowptr, const int* __restrict__ deg,
                               const int* __restrict__ esrc,
                               const float* __restrict__ au, const float* __restrict__ av,
                               const bf16* __restrict__ h, bf16* __restrict__ agg, int N) {
    const int node = (blockIdx.x * 256 + threadIdx.x) >> 6;
    if (node >= N) return;
    const int lane = threadIdx.x & 63;
    const int e = lane >> 3;          // which edge of the 8-batch
    const int head = lane & 7;        // lane's single head
    const int d0b = head * 32;        // byte offset of its 16 head-major dims
    const char* hpb = (const char*)h;
    const int nd = deg[node];
    const int start = rowptr[node];
    const float avh = av[((size_t)node << 3) + head];
    const int* ep = esrc + start;

    float l0 = 0.f;
    float o[16];
    #pragma unroll
    for (int j = 0; j < 16; ++j) o[j] = 0.f;

    int i = 0;
    for (; i + 16 <= nd; i += 16) {
        do8e<false>(ep, i, nd, e, head, d0b, au, hpb, avh, l0, o);
        do8e<false>(ep, i + 8, nd, e, head, d0b, au, hpb, avh, l0, o);
    }
    if (i + 8 <= nd) { do8e<false>(ep, i, nd, e, head, d0b, au, hpb, avh, l0, o); i += 8; }
    if (i < nd) do8e<true>(ep, i, nd, e, head, d0b, au, hpb, avh, l0, o);

    // sum the 8 edge-groups (lanes l, l^8, l^16, ..., l^56 own the same dims)
    #pragma unroll
    for (int j = 0; j < 16; ++j) {
        o[j] += __shfl_xor(o[j], 8);
        o[j] += __shfl_xor(o[j], 16);
        o[j] += __shfl_xor(o[j], 32);
    }
    l0 += __shfl_xor(l0, 8);
    l0 += __shfl_xor(l0, 16);
    l0 += __shfl_xor(l0, 32);

    if (lane < 8) {
        float inv = l0 > 0.f ? 1.f / l0 : 0.f;   // deg-0 -> 0 (matches segment_sum)
        unsigned r[8];
        #pragma unroll
        for (int j = 0; j < 8; ++j)
            r[j] = ((unsigned)f2bf(o[2 * j + 1] * inv) << 16) | (unsigned)f2bf(o[2 * j] * inv);
        char* outp = (char*)agg + ((size_t)node << 8) + lane * 32;
        *(uint4*)outp = (uint4){r[0], r[1], r[2], r[3]};
        *(uint4*)(outp + 16) = (uint4){r[4], r[5], r[6], r[7]};
    }
}

extern "C" void kernel_launch(void* const* d_in, const int* in_sizes, int n_in,
                              void* d_out, int out_size, void* d_ws, size_t ws_size,
                              hipStream_t stream) {
    const float* x    = (const float*)d_in[0];
    const int*   src  = (const int*)d_in[1];
    const int*   dst  = (const int*)d_in[2];
    const float* w_in = (const float*)d_in[3];
    const float* b_in = (const float*)d_in[4];
    const float* w_au = (const float*)d_in[5];
    const float* b_au = (const float*)d_in[6];
    const float* w_av = (const float*)d_in[7];
    const float* w1   = (const float*)d_in[8];
    const float* b1   = (const float*)d_in[9];
    const float* w2   = (const float*)d_in[10];
    const float* b2   = (const float*)d_in[11];
    const int N = in_sizes[0] / DIM;
    const int E = in_sizes[1];
    const int K = (N + BK - 1) / BK;      // buckets (<=1024 for N<=131072)
    const int B = (E + CH - 1) / CH;      // bucketing blocks

    // workspace ~65.2 MB
    char* p = (char*)d_ws;
    int*  deg    = (int*)p;  p += (size_t)N * 4;          //  0.4 MB
    int*  rowptr = (int*)p;  p += (size_t)N * 4;          //  0.4 MB
    int*  esrc   = (int*)p;  p += (size_t)E * 4;          //  6.4 MB
    bf16* h      = (bf16*)p; p += (size_t)N * DIM * 2;    // 25.6 MB head-major
    float* au    = (float*)p; p += (size_t)N * NH * 4;    //  3.2 MB
    float* av    = (float*)p; p += (size_t)N * NH * 4;    //  3.2 MB
    unsigned short* w_in_b = (unsigned short*)p; p += 128 * 128 * 2;   // 32 KB bf16 wt-layout
    unsigned short* w1_b   = (unsigned short*)p; p += 128 * 128 * 2;   // 32 KB (PERM applied)
    unsigned short* w2_b   = (unsigned short*)p; p += 128 * 128 * 2;   // 32 KB
    unsigned short* wc_b   = (unsigned short*)p; p += 16 * 128 * 2;    //  4 KB (PERM applied)
    int* total = (int*)p; p += 64;                                     //  alloc counter
    bf16* agg    = (bf16*)p;  p += (size_t)N * DIM * 2;   // 25.6 MB head-major
    // build-time scratch overlaid into agg (dead until agg_csr runs):
    unsigned* packed = (unsigned*)agg;                          // B*CH*4 ~ 6.4 MB
    int* mat   = (int*)((char*)agg + (size_t)B * CH * 4);       // B*1024*4 ~ 1.6 MB (B-major)
    int* matx  = mat + (size_t)B * 1024;                        // K*B*4 ~ 1.25 MB (K-major)
    int* btot  = matx + (size_t)K * B;                          // K*4
    int* bbase = btot + K;                                      // K*4
    int* lofs  = bbase + K;                                     // B*K*4 ~ 1.25 MB

    const int row_blocks = (N + 127) / 128;

    scatter_pre_kernel<<<B + 13, 256, 0, stream>>>(src, dst, lofs, mat, packed, total,
                                                   E, K, B, w_in, w1, w2, w_au, w_av,
                                                   w_in_b, w1_b, w2_b, wc_b);

    gia_scan_kernel<<<row_blocks + K, 512, 0, stream>>>(x, w_in_b, b_in, wc_b, b_au,
                                                        h, au, av, N, row_blocks,
                                                        mat, matx, btot, bbase, total, K, B);

    bucket_csr_kernel<<<K, 256, 0, stream>>>(packed, lofs, matx, bbase, btot,
                                             rowptr, deg, esrc, N, E, K, B);

    agg_csr_kernel<<<(N + 3) / 4, 256, 0, stream>>>(rowptr, deg, esrc, au, av, h, agg, N);

    ff_kernel<<<row_blocks, 512, 0, stream>>>(agg, w1_b, b1, w2_b, b2, (float*)d_out, N);
}